// Round 6
// baseline (177.895 us; speedup 1.0000x reference)
//
#include <hip/hip_runtime.h>
#include <hip/hip_bf16.h>

// B=4, S=2048, D=512. fp32 in/out, bf16 MFMA internals.
// Key identity: multiplicative causal mask => E = 1 + F, F = expm1(scale*s) on
// the lower triangle (q>=k), 0 above. Then
//   out  = F @ vp'  +  T,   T[b,d] = sum_k vp'[b,k,d]
//   Z[k] = 2048 + colsum(F)
// Pipeline: cvt_all | proj3 | scoresF | scaleT | outF
//
// R5: proj/scores GEMM core rebuilt as a 4-buffer BK=64 deep pipeline:
//     128 KB LDS (4 x 32 KB), 1 block/CU, prefetch distance 3 (~750 cyc,
//     covers HBM latency), counted WAITV(16) so 2 tiles stay in flight, ONE
//     barrier per K-tile (safe: every wave does lgkmcnt(0) before its barrier
//     arrival, so buf (kt-1)&3 is dead when tile kt+3 is staged into it).
//     K fixed at 512 (8 K-tiles). BK=32 is permanently rejected: 64 B rows
//     with 16 B lane-reads touch only 8 bank slots => >=4-way conflict by
//     construction (R1's measured 4.3M conflicts).
//     outF: new XCD-aware mapping — the 4 N-blocks sharing one F tile land on
//     one XCD (F ~32 MB > L2; cuts ~3x refetch) with equal per-XCD K-work.

#define S_LEN 2048
#define D_DIM 512
#define SCALE_F 0.044194173824159216f  // 1/sqrt(512)

typedef __attribute__((ext_vector_type(8))) short s8v;   // 8 bf16 = 4 VGPRs
typedef __attribute__((ext_vector_type(4))) short s4v;   // 4 bf16 = 8 B
typedef __attribute__((ext_vector_type(4))) float f4v;   // MFMA accumulator

enum { EPI_BIAS = 0, EPI_BIAS_T = 1, EPI_SCORES = 2 };

#define SBAR()    __builtin_amdgcn_s_barrier()
#define SCHEDB()  __builtin_amdgcn_sched_barrier(0)
#define WAITV(n)  asm volatile("s_waitcnt vmcnt(" #n ")")
#define WAITL0()  asm volatile("s_waitcnt lgkmcnt(0)")

__device__ __forceinline__ short f2bf_s(float f) {
  union { __hip_bfloat16 b; short s; } u; u.b = __float2bfloat16(f); return u.s;
}
__device__ __forceinline__ float bf2f_s(short h) {
  union { short s; __hip_bfloat16 b; } u; u.s = h; return __bfloat162float(u.b);
}

__device__ __forceinline__ void glds16(const short* g, short* l) {
  __builtin_amdgcn_global_load_lds((const __attribute__((address_space(1))) void*)g,
                                   (__attribute__((address_space(3))) void*)l, 16, 0, 0);
}

// LDS byte offset of a __shared__-derived pointer (addrspace(3) is 32-bit).
__device__ __forceinline__ unsigned lds_addr(const short* p) {
  return (unsigned)(unsigned long long)(const __attribute__((address_space(3))) short*)p;
}

// Inline-asm ds_read_b128: keeps the counted WAITV authoritative. MUST be
// followed by lgkmcnt(0)+SCHEDB before any consumer (rule 18).
__device__ __forceinline__ s8v dsr128(unsigned a) {
  s8v r;
  asm volatile("ds_read_b128 %0, %1" : "=&v"(r) : "v"(a));
  return r;
}

// Core NT GEMM, 128x128 tile at (m0,n0), K=512 fixed (8 K-tiles of 64).
// 4 LDS buffers (kt&3) of 32 KB: As=+0 (128 rows x 128 B), Bs=+16 KB.
// Prologue stages tiles 0,1,2. Per K-tile kt: WAITV(counted: tile kt landed,
// kt+1/kt+2 in flight) -> SBAR -> stage kt+3 into buf (kt-1)&3 -> 2 phases of
// {8 asm ds_read, lgkmcnt(0), setprio(1), 16 MFMA, setprio(0)}.
template <int EPI>
__device__ __forceinline__ void gemm_core512(
    const short* __restrict__ A, const short* __restrict__ B,
    short* __restrict__ C, const float* __restrict__ bias,
    short* SMEM, int N, size_t sCz, int m0, int n0, int bz,
    float* __restrict__ Z)
{
  const int tid  = threadIdx.x;
  const int w    = tid >> 6;
  const int lane = tid & 63;
  const int quad = lane >> 4;
  const int l16  = lane & 15;
  const int wm   = (w >> 1) * 64;
  const int wn   = (w & 1) * 64;

  const int strow = tid >> 3;                         // 0..31
  const int gl = ((tid & 7) ^ (strow & 7)) * 8;       // XOR column-octet swizzle

  f4v acc[4][4];
#pragma unroll
  for (int i = 0; i < 4; ++i)
#pragma unroll
    for (int j = 0; j < 4; ++j)
#pragma unroll
      for (int r = 0; r < 4; ++r) acc[i][j][r] = 0.0f;

  const short* Ag = A + (size_t)(m0 + strow) * 512 + gl;
  const short* Bg = B + (size_t)(n0 + strow) * 512 + gl;
  const size_t pstr = (size_t)32 * 512;
  const int t8 = tid * 8;
  const int swq = l16 & 7;

  const unsigned base = lds_addr(SMEM);
  unsigned aoff[4], boff[4];
#pragma unroll
  for (int ii = 0; ii < 4; ++ii)
    aoff[ii] = base + (unsigned)((wm + ii * 16 + l16) * 128 + ((quad ^ swq) * 16));
#pragma unroll
  for (int j = 0; j < 4; ++j)
    boff[j] = base + 16384u + (unsigned)((wn + j * 16 + l16) * 128 + ((quad ^ swq) * 16));

  // stage tile kt into buffer b (8 glds16/wave)
#define STAGE512(kt, b)                                                        \
  {                                                                            \
    short* dst_ = SMEM + (b) * 16384 + t8;                                     \
    const int ko_ = (kt) << 6;                                                 \
    _Pragma("unroll")                                                          \
    for (int p = 0; p < 4; ++p) glds16(Ag + ko_ + p * pstr, dst_ + p * 2048);  \
    _Pragma("unroll")                                                          \
    for (int p = 0; p < 4; ++p) glds16(Bg + ko_ + p * pstr, dst_ + 8192 + p * 2048); \
  }

  STAGE512(0, 0);
  STAGE512(1, 1);
  STAGE512(2, 2);

  for (int kt = 0; kt < 8; ++kt) {
    if (kt <= 5)      { WAITV(16); }   // tiles kt+1,kt+2 (16 instr) in flight
    else if (kt == 6) { WAITV(8);  }
    else              { WAITV(0);  }
    SBAR();
    SCHEDB();

    if (kt < 5) STAGE512(kt + 3, (kt + 3) & 3);

    const unsigned cofs = (unsigned)((kt & 3) * 32768);
#pragma unroll
    for (int kk = 0; kk < 2; ++kk) {
      const unsigned kx = (unsigned)(kk << 6);
      s8v af[4], bf[4];
#pragma unroll
      for (int ii = 0; ii < 4; ++ii) af[ii] = dsr128((aoff[ii] ^ kx) + cofs);
#pragma unroll
      for (int j = 0; j < 4; ++j)   bf[j]  = dsr128((boff[j] ^ kx) + cofs);
      WAITL0();
      SCHEDB();
      __builtin_amdgcn_s_setprio(1);
#pragma unroll
      for (int ii = 0; ii < 4; ++ii)
#pragma unroll
        for (int j = 0; j < 4; ++j)
          acc[ii][j] = __builtin_amdgcn_mfma_f32_16x16x32_bf16(af[ii], bf[j], acc[ii][j], 0, 0, 0);
      __builtin_amdgcn_s_setprio(0);
    }
  }
#undef STAGE512

  // ---- epilogue ----
  float bv[4];
  if (EPI == EPI_BIAS || EPI == EPI_BIAS_T) {
#pragma unroll
    for (int j = 0; j < 4; ++j) bv[j] = bias[n0 + wn + j * 16 + l16];
  }

  if (EPI == EPI_BIAS_T) {
#pragma unroll
    for (int i = 0; i < 4; ++i) {
#pragma unroll
      for (int j = 0; j < 4; ++j) {
        const int gn  = n0 + wn + j * 16 + l16;
        const int gmb = m0 + wm + i * 16 + quad * 4;
        const int bb = gmb >> 11, ssb = gmb & (S_LEN - 1);
        s4v o;
#pragma unroll
        for (int r = 0; r < 4; ++r) o[r] = f2bf_s(acc[i][j][r] + bv[j]);
        *(s4v*)&C[((size_t)bb * D_DIM + gn) * S_LEN + ssb] = o;
      }
    }
    return;
  }

  // EPI_BIAS / EPI_SCORES: LDS transpose -> coalesced 16B row stores.
  short* TB = SMEM;                 // 4 waves x 2176 shorts (32 rows x stride 68)
  const int wbase = w * 2176;
  float csum[4] = {0.f, 0.f, 0.f, 0.f};

#pragma unroll
  for (int ph = 0; ph < 2; ++ph) {
    __syncthreads();
#pragma unroll
    for (int ii = 0; ii < 2; ++ii) {
      const int i = ph * 2 + ii;
#pragma unroll
      for (int j = 0; j < 4; ++j) {
        const int gn = n0 + wn + j * 16 + l16;
#pragma unroll
        for (int r = 0; r < 4; ++r) {
          short o;
          if (EPI == EPI_SCORES) {
            const int gm = m0 + wm + i * 16 + quad * 4 + r;
            const float f = (gm >= gn) ? (__expf(acc[i][j][r] * SCALE_F) - 1.0f) : 0.0f;
            csum[j] += f;
            o = f2bf_s(f);
          } else {
            o = f2bf_s(acc[i][j][r] + bv[j]);
          }
          TB[wbase + (ii * 16 + quad * 4 + r) * 68 + j * 16 + l16] = o;
        }
      }
    }
    __syncthreads();
#pragma unroll
    for (int p = 0; p < 4; ++p) {
      const int row = p * 8 + (lane >> 3);   // 0..31
      const int cg  = lane & 7;
      const s8v vv = *(const s8v*)&TB[wbase + row * 68 + cg * 8];
      const int gm = m0 + wm + ph * 32 + row;
      const int gn = n0 + wn + cg * 8;
      *(s8v*)&C[sCz + (size_t)gm * N + gn] = vv;
    }
  }

  if (EPI == EPI_SCORES) {
#pragma unroll
    for (int j = 0; j < 4; ++j) {
      float cs = csum[j];
      cs += __shfl_xor(cs, 16, 64);
      cs += __shfl_xor(cs, 32, 64);
      if (quad == 0) atomicAdd(&Z[(bz << 11) + n0 + wn + j * 16 + l16], cs);
    }
  }
}

// scores-F kernel: 1-D grid 544 (=8x68, XCD-bijective swizzle), tri tiles.
__global__ __launch_bounds__(256, 1) void gemm_scoresF(
    const short* __restrict__ A, const short* __restrict__ B, short* __restrict__ C,
    float* __restrict__ Z)
{
  __shared__ __align__(16) short SMEM[65536];   // 128 KB (4 bufs)
  const int bid = blockIdx.x;
  const int bsw = (bid & 7) * 68 + (bid >> 3);  // consecutive bsw share one XCD
  const int bz  = bsw / 136;
  const int t   = bsw - bz * 136;
  int ti = (int)((sqrtf(8.0f * t + 1.0f) - 1.0f) * 0.5f);
  while ((ti + 1) * (ti + 2) / 2 <= t) ++ti;
  while (ti * (ti + 1) / 2 > t) --ti;
  const int tj = t - ti * (ti + 1) / 2;         // tj <= ti
  gemm_core512<EPI_SCORES>(A + (size_t)bz * S_LEN * D_DIM, B + (size_t)bz * S_LEN * D_DIM,
                           C, nullptr, SMEM, S_LEN,
                           (size_t)bz * S_LEN * S_LEN, ti * 128, tj * 128, bz, Z);
}

// projections: 1-D grid 768 (=8x96, XCD-bijective swizzle), z from id.
__global__ __launch_bounds__(256, 1) void proj3(
    const short* __restrict__ a0, const short* __restrict__ a1, const short* __restrict__ a2,
    const short* __restrict__ b0, const short* __restrict__ b1, const short* __restrict__ b2,
    short* __restrict__ c0, short* __restrict__ c1, short* __restrict__ c2,
    const float* __restrict__ x0, const float* __restrict__ x1, const float* __restrict__ x2)
{
  __shared__ __align__(16) short SMEM[65536];   // 128 KB (4 bufs)
  const int bid = blockIdx.x;
  const int bsw = (bid & 7) * 96 + (bid >> 3);
  const int z   = bsw >> 8;
  const int rem = bsw & 255;
  const int m0  = (rem >> 2) * 128;
  const int n0  = (rem & 3) * 128;
  const short* A = (z == 0) ? a0 : (z == 1) ? a1 : a2;
  const short* B = (z == 0) ? b0 : (z == 1) ? b1 : b2;
  short*       C = (z == 0) ? c0 : (z == 1) ? c1 : c2;
  const float* bias = (z == 0) ? x0 : (z == 1) ? x1 : x2;
  if (z == 2)
    gemm_core512<EPI_BIAS_T>(A, B, C, bias, SMEM, D_DIM, 0, m0, n0, 0, nullptr);
  else
    gemm_core512<EPI_BIAS>(A, B, C, bias, SMEM, D_DIM, 0, m0, n0, 0, nullptr);
}

// out = F @ vpT'^T + T, 64x128 tiles, BK=64, K truncated at m0+64,
// triple-buffered (72 KB), prefetch distance 2 issued AFTER the barrier.
// Grid 512 1-D, XCD-aware balanced mapping: x=h&7 (XCD under round-robin),
// s=h>>3: n0=(s&3)*128, bz=(s>>2)&3, zslot=s>>4 in 0..3 ->
// zs = zslot<2 ? 2x+zslot : 16+2x+(zslot-2). The 4 N-blocks of one F tile are
// consecutive s on one XCD (F-tile fetched once per XCD, not 4x from HBM);
// per-XCD K-work is equal (66 K-tiles per bz); long tiles dispatch first.
__global__ __launch_bounds__(256, 2) void gemm_outF(
    const short* __restrict__ F, const short* __restrict__ vpT,
    const float* __restrict__ Tv, float* __restrict__ out)
{
  __shared__ __align__(16) short SMEM[36864];   // 72 KB

  const int tid  = threadIdx.x;
  const int h    = blockIdx.x;
  const int x    = h & 7;
  const int s    = h >> 3;
  const int n0   = (s & 3) * 128;
  const int bz   = (s >> 2) & 3;
  const int zslot = s >> 4;                     // 0..3
  const int zs   = (zslot < 2) ? (2 * x + zslot) : (16 + 2 * x + (zslot - 2));
  const int mi   = (zs < 16) ? (31 - zs) : (zs - 16);
  const int m0   = mi * 64;

  const short* A = F   + (size_t)bz * S_LEN * S_LEN;
  const short* B = vpT + (size_t)bz * D_DIM * S_LEN;

  const int w    = tid >> 6;
  const int lane = tid & 63;
  const int quad = lane >> 4;
  const int l16  = lane & 15;
  const int wm   = (w >> 1) * 32;
  const int wn   = (w & 1) * 64;

  const int strow = tid >> 3;
  const int gl = ((tid & 7) ^ (strow & 7)) * 8;

  f4v acc[2][4];
#pragma unroll
  for (int i = 0; i < 2; ++i)
#pragma unroll
    for (int j = 0; j < 4; ++j)
#pragma unroll
      for (int r = 0; r < 4; ++r) acc[i][j][r] = 0.0f;

  const short* Ag = A + (size_t)(m0 + strow) * S_LEN + gl;
  const short* Bg = B + (size_t)(n0 + strow) * S_LEN + gl;
  const size_t pstr = (size_t)32 * S_LEN;
  const int t8 = tid * 8;
  const int swq = l16 & 7;

  const unsigned base = lds_addr(SMEM);
  unsigned aoff[2], boff[4];
#pragma unroll
  for (int ii = 0; ii < 2; ++ii)
    aoff[ii] = base + (unsigned)((wm + ii * 16 + l16) * 128 + ((quad ^ swq) * 16));
#pragma unroll
  for (int j = 0; j < 4; ++j)
    boff[j] = base + 8192u + (unsigned)((wn + j * 16 + l16) * 128 + ((quad ^ swq) * 16));

  const int niter = mi + 1;   // K runs 0 .. m0+64

  // preload tiles 0,1 into bufs 0,1 (6 loads each: A x2, B x4)
#pragma unroll
  for (int pre = 0; pre < 2; ++pre) {
    short* dst = SMEM + pre * 12288 + t8;
    const int k0 = pre << 6;
#pragma unroll
    for (int p = 0; p < 2; ++p) glds16(Ag + k0 + p * pstr, dst + p * 2048);
#pragma unroll
    for (int p = 0; p < 4; ++p) glds16(Bg + k0 + p * pstr, dst + 4096 + p * 2048);
  }

  int cbuf = 0;
  for (int i = 0; i < niter; ++i) {
    if (i + 1 < niter) { WAITV(6); } else { WAITV(0); }   // tile i landed
    SBAR();
    SCHEDB();

    if (i + 2 < niter) {          // issue i+2 into the buffer read at i-1
      int nb = cbuf + 2; if (nb >= 3) nb -= 3;
      const int k2 = (i + 2) << 6;
      short* dst = SMEM + nb * 12288 + t8;
#pragma unroll
      for (int p = 0; p < 2; ++p) glds16(Ag + k2 + p * pstr, dst + p * 2048);
#pragma unroll
      for (int p = 0; p < 4; ++p) glds16(Bg + k2 + p * pstr, dst + 4096 + p * 2048);
      SCHEDB();
    }

    const unsigned cofs = (unsigned)(cbuf * 24576);
    cbuf = (cbuf == 2) ? 0 : cbuf + 1;
#pragma unroll
    for (int kk = 0; kk < 2; ++kk) {
      const unsigned kx = (unsigned)(kk << 6);
      s8v af[2], bf[4];
#pragma unroll
      for (int ii = 0; ii < 2; ++ii) af[ii] = dsr128((aoff[ii] ^ kx) + cofs);
#pragma unroll
      for (int j = 0; j < 4; ++j)   bf[j]  = dsr128((boff[j] ^ kx) + cofs);
      WAITL0();
      SCHEDB();
      __builtin_amdgcn_s_setprio(1);
#pragma unroll
      for (int ii = 0; ii < 2; ++ii)
#pragma unroll
        for (int j = 0; j < 4; ++j)
          acc[ii][j] = __builtin_amdgcn_mfma_f32_16x16x32_bf16(af[ii], bf[j], acc[ii][j], 0, 0, 0);
      __builtin_amdgcn_s_setprio(0);
    }
  }

  float* Cf = out + (size_t)bz * S_LEN * D_DIM;
#pragma unroll
  for (int i = 0; i < 2; ++i) {
#pragma unroll
    for (int j = 0; j < 4; ++j) {
      const int gn = n0 + wn + j * 16 + l16;
      const float tvn = Tv[(bz << 9) + gn];
#pragma unroll
      for (int r = 0; r < 4; ++r) {
        const int gm = m0 + wm + i * 16 + quad * 4 + r;
        Cf[(size_t)gm * D_DIM + gn] = acc[i][j][r] + tvn;
      }
    }
  }
}

// fp32 -> bf16, one launch for data (x<2048) and weights (x>=2048).
__global__ __launch_bounds__(256) void cvt_all(
    const float* __restrict__ q, const float* __restrict__ k, const float* __restrict__ v,
    const float* __restrict__ wq, const float* __restrict__ wk, const float* __restrict__ wv,
    short* __restrict__ qb, short* __restrict__ Wqb)
{
  const int y = blockIdx.y;
  const float* s; short* d; int i;
  if (blockIdx.x < 2048) {
    s = (y == 0) ? q : (y == 1) ? k : v;
    d = qb + (size_t)y * 4194304;
    i = (blockIdx.x * 256 + threadIdx.x) * 8;
  } else {
    s = (y == 0) ? wq : (y == 1) ? wk : wv;
    d = Wqb + (size_t)y * 262144;
    i = ((int)(blockIdx.x - 2048) * 256 + threadIdx.x) * 8;
  }
  const float4 f0 = *(const float4*)(s + i);
  const float4 f1 = *(const float4*)(s + i + 4);
  s8v o;
  o[0] = f2bf_s(f0.x); o[1] = f2bf_s(f0.y); o[2] = f2bf_s(f0.z); o[3] = f2bf_s(f0.w);
  o[4] = f2bf_s(f1.x); o[5] = f2bf_s(f1.y); o[6] = f2bf_s(f1.z); o[7] = f2bf_s(f1.w);
  *(s8v*)(d + i) = o;
}

// block per (b,d): vpT[b][d][k] /= (2048+ZF[b][k]); Tv[b,d] = sum_k (fp32)
__global__ __launch_bounds__(256) void scale_vpt_T(
    short* __restrict__ vpT, const float* __restrict__ ZF, float* __restrict__ Tv)
{
  __shared__ float red[4];
  const int b = blockIdx.y, d = blockIdx.x, tid = threadIdx.x;
  const size_t rowbase = ((size_t)(b * D_DIM + d)) * S_LEN;
  const float* zf = ZF + (b << 11);
  const int k0 = tid * 8;

  s8v v = *(s8v*)&vpT[rowbase + k0];
  float s = 0.0f;
#pragma unroll
  for (int i = 0; i < 8; ++i) {
    const float w = bf2f_s(v[i]) / (2048.0f + zf[k0 + i]);
    s += w;
    v[i] = f2bf_s(w);
  }
  *(s8v*)&vpT[rowbase + k0] = v;

#pragma unroll
  for (int off = 32; off >= 1; off >>= 1) s += __shfl_xor(s, off, 64);
  if ((tid & 63) == 0) red[tid >> 6] = s;
  __syncthreads();
  if (tid == 0) Tv[(b << 9) + d] = red[0] + red[1] + red[2] + red[3];
}

extern "C" void kernel_launch(void* const* d_in, const int* in_sizes, int n_in,
                              void* d_out, int out_size, void* d_ws, size_t ws_size,
                              hipStream_t stream) {
  const float* q   = (const float*)d_in[0];
  const float* k   = (const float*)d_in[1];
  const float* v   = (const float*)d_in[2];
  const float* WQw = (const float*)d_in[3];
  const float* WQb = (const float*)d_in[4];
  const float* WKw = (const float*)d_in[5];
  const float* WKb = (const float*)d_in[6];
  const float* WVw = (const float*)d_in[7];
  const float* WVb = (const float*)d_in[8];

  char* ws = (char*)d_ws;
  // F occupies [0,32M); bf16 input/weight copies alias its head (dead before F written)
  short* F   = (short*)(ws);                 // 32 MB  [4][2048][2048] (lower tiles only)
  short* qb  = (short*)(ws);                 //  8 MB  (qb,kb,vb contiguous)
  short* Wqb = (short*)(ws + 25165824);      // 3x 512 KB contiguous
  short* qp  = (short*)(ws + 33554432);      //  8 MB  [4][2048][512]
  short* kp  = (short*)(ws + 41943040);      //  8 MB
  short* vpT = (short*)(ws + 50331648);      //  8 MB  [4][512][2048]
  float* ZF  = (float*)(ws + 58720256);      // 32 KB  [4][2048]
  float* Tv  = (float*)(ws + 58753024);      //  8 KB  [4][512]
  short* kb  = qb + 4194304;
  short* vb  = qb + 8388608;
  short* Wkb = Wqb + 262144;
  short* Wvb = Wqb + 524288;

  const dim3 blk(256);

  (void)hipMemsetAsync(ZF, 0, 4 * S_LEN * sizeof(float), stream);

  cvt_all<<<dim3(2176, 3), blk, 0, stream>>>(q, k, v, WQw, WKw, WVw, qb, Wqb);

  // projections: M=8192, N=512, K=512 — 768 blocks = 3 exact rounds @1/CU
  proj3<<<dim3(768), blk, 0, stream>>>(
      qb, kb, vb, Wqb, Wkb, Wvb, qp, kp, vpT, WQb, WKb, WVb);

  // F = expm1(scale*qp@kp^T) lower-tri tiles + fused ZF colsum: 544 blocks
  gemm_scoresF<<<dim3(544), blk, 0, stream>>>(qp, kp, F, ZF);

  // vpT' = vpT/(2048+ZF); Tv = rowsum(vpT')
  scale_vpt_T<<<dim3(512, 4), blk, 0, stream>>>(vpT, ZF, Tv);

  // out = F @ vpT'^T + Tv: 64x128 tiles, K truncated at m0+64, XCD-balanced
  gemm_outF<<<dim3(512), blk, 0, stream>>>(F, vpT, Tv, (float*)d_out);
}